// Round 2
// baseline (12290.546 us; speedup 1.0000x reference)
//
#include <hip/hip_runtime.h>

// LightGCN propagation on MI355X.
// out = emb + A@emb/2 + A^2@emb/3 + A^3@emb/4, A given as COO (rows, cols, vals).
// N = 150000 nodes, D = 64, E = 4.8M edges.

#define NNODES 150000
#define EDIM   64

// One 16-lane quarter-wave per edge; lane owns 4 consecutive dims (float4).
// Interleaved edge assignment: the 4 quarter-waves of a wave process
// consecutive edges, so edge-array reads coalesce at wave level.
// Gather x[col][:] (256B coalesced per edge), scale by val, atomic-scatter
// into y[row][:].
__global__ __launch_bounds__(256) void spmm_kernel(
    const int* __restrict__ rows, const int* __restrict__ cols,
    const float* __restrict__ vals, const float* __restrict__ x,
    float* __restrict__ y, int E, int nqw)
{
    const int gtid = blockIdx.x * blockDim.x + threadIdx.x;
    const int qw   = gtid >> 4;          // quarter-wave id = edge worker
    const int l4   = (gtid & 15) * 4;    // 4-float slice within the 64-dim row

    for (int e = qw; e < E; e += nqw) {
        const int   c = cols[e];
        const int   r = rows[e];
        const float v = vals[e];
        const float4 xv = *reinterpret_cast<const float4*>(x + c * EDIM + l4);
        float* yp = y + r * EDIM + l4;
        atomicAdd(yp + 0, xv.x * v);
        atomicAdd(yp + 1, xv.y * v);
        atomicAdd(yp + 2, xv.z * v);
        atomicAdd(yp + 3, xv.w * v);
    }
}

// out = emb + x1/2 + x2/3 + x3/4   (fused, float4)
__global__ __launch_bounds__(256) void finalize3_kernel(
    const float4* __restrict__ emb, const float4* __restrict__ x1,
    const float4* __restrict__ x2, const float4* __restrict__ x3,
    float4* __restrict__ out, int n4)
{
    int i = blockIdx.x * blockDim.x + threadIdx.x;
    const int stride = gridDim.x * blockDim.x;
    for (; i < n4; i += stride) {
        const float4 e = emb[i], a = x1[i], b = x2[i], c = x3[i];
        float4 o;
        o.x = e.x + 0.5f * a.x + (1.0f / 3.0f) * b.x + 0.25f * c.x;
        o.y = e.y + 0.5f * a.y + (1.0f / 3.0f) * b.y + 0.25f * c.y;
        o.z = e.z + 0.5f * a.z + (1.0f / 3.0f) * b.z + 0.25f * c.z;
        o.w = e.w + 0.5f * a.w + (1.0f / 3.0f) * b.w + 0.25f * c.w;
        out[i] = o;
    }
}

// out = emb + c*x   (2-buffer fallback path)
__global__ __launch_bounds__(256) void combine_kernel(
    const float4* __restrict__ emb, const float4* __restrict__ x,
    float c, float4* __restrict__ out, int n4)
{
    int i = blockIdx.x * blockDim.x + threadIdx.x;
    const int stride = gridDim.x * blockDim.x;
    for (; i < n4; i += stride) {
        const float4 e = emb[i], a = x[i];
        float4 o;
        o.x = e.x + c * a.x;
        o.y = e.y + c * a.y;
        o.z = e.z + c * a.z;
        o.w = e.w + c * a.w;
        out[i] = o;
    }
}

// out += c*x   (2-buffer fallback path)
__global__ __launch_bounds__(256) void accum_kernel(
    float4* __restrict__ out, const float4* __restrict__ x, float c, int n4)
{
    int i = blockIdx.x * blockDim.x + threadIdx.x;
    const int stride = gridDim.x * blockDim.x;
    for (; i < n4; i += stride) {
        const float4 o0 = out[i], a = x[i];
        float4 o;
        o.x = o0.x + c * a.x;
        o.y = o0.y + c * a.y;
        o.z = o0.z + c * a.z;
        o.w = o0.w + c * a.w;
        out[i] = o;
    }
}

extern "C" void kernel_launch(void* const* d_in, const int* in_sizes, int n_in,
                              void* d_out, int out_size, void* d_ws, size_t ws_size,
                              hipStream_t stream)
{
    const int*   rows = (const int*)  d_in[0];
    const int*   cols = (const int*)  d_in[1];
    const float* vals = (const float*)d_in[2];
    const float* emb  = (const float*)d_in[3];
    float*       out  = (float*)d_out;

    const int E  = in_sizes[0];
    const int n  = NNODES * EDIM;          // 9,600,000 floats
    const int n4 = n / 4;
    const size_t bufBytes = (size_t)n * sizeof(float);   // 38.4 MB

    float* wsA = (float*)d_ws;
    float* wsB = wsA + n;
    float* wsC = wsB + n;

    // SpMM launch geometry: 2048 blocks * 256 thr = 32768 edge workers
    // (8 blocks/CU, full 32-wave occupancy).
    const int NQW     = 32768;
    const int sblocks = NQW / 16;          // 2048 blocks of 256 threads
    const int eblocks = 2048;              // elementwise kernels

    if (ws_size >= 3 * bufBytes) {
        // 3-buffer path: one memset, three SpMMs, one fused finalize.
        hipMemsetAsync(d_ws, 0, 3 * bufBytes, stream);
        spmm_kernel<<<sblocks, 256, 0, stream>>>(rows, cols, vals, emb, wsA, E, NQW);
        spmm_kernel<<<sblocks, 256, 0, stream>>>(rows, cols, vals, wsA, wsB, E, NQW);
        spmm_kernel<<<sblocks, 256, 0, stream>>>(rows, cols, vals, wsB, wsC, E, NQW);
        finalize3_kernel<<<eblocks, 256, 0, stream>>>(
            (const float4*)emb, (const float4*)wsA, (const float4*)wsB,
            (const float4*)wsC, (float4*)out, n4);
    } else {
        // 2-buffer path: incremental accumulation.
        hipMemsetAsync(d_ws, 0, 2 * bufBytes, stream);
        spmm_kernel<<<sblocks, 256, 0, stream>>>(rows, cols, vals, emb, wsA, E, NQW);
        combine_kernel<<<eblocks, 256, 0, stream>>>(
            (const float4*)emb, (const float4*)wsA, 0.5f, (float4*)out, n4);
        spmm_kernel<<<sblocks, 256, 0, stream>>>(rows, cols, vals, wsA, wsB, E, NQW);
        accum_kernel<<<eblocks, 256, 0, stream>>>(
            (float4*)out, (const float4*)wsB, 1.0f / 3.0f, n4);
        hipMemsetAsync(wsA, 0, bufBytes, stream);
        spmm_kernel<<<sblocks, 256, 0, stream>>>(rows, cols, vals, wsB, wsA, E, NQW);
        accum_kernel<<<eblocks, 256, 0, stream>>>(
            (float4*)out, (const float4*)wsA, 0.25f, n4);
    }
}

// Round 4
// 1487.612 us; speedup vs baseline: 8.2619x; 8.2619x over previous
//
#include <hip/hip_runtime.h>

// LightGCN propagation on MI355X.
// out = emb + A@emb/2 + A^2@emb/3 + A^3@emb/4, A given as COO (rows, cols, vals).
// N = 150000 nodes, D = 64, E = 4.8M edges.
//
// Strategy: on-device COO->CSR counting sort each call (the scatter-atomic COO
// SpMM was write-through bound: 4.8 GB HBM writes per layer = 16B per f32
// atomic). CSR segment-sum accumulates each row in registers -> zero feature
// atomics, plain stores, and the emb + sum(xk/(k+1)) accumulation fuses into
// the layer kernels.

#define NNODES 150000
#define EDIM   64

// ---------------- CSR build ----------------

__global__ __launch_bounds__(256) void hist_kernel(
    const int* __restrict__ rows, int* __restrict__ hist, int E)
{
    int i = blockIdx.x * blockDim.x + threadIdx.x;
    const int stride = gridDim.x * blockDim.x;
    for (; i < E; i += stride) atomicAdd(&hist[rows[i]], 1);
}

// Single-block exclusive scan of the 150k histogram -> row_ptr (+ cursor copy).
__global__ __launch_bounds__(1024) void scan_kernel(
    const int* __restrict__ hist, int* __restrict__ row_ptr,
    int* __restrict__ cursor)
{
    __shared__ int tsum[1024];
    const int tid   = threadIdx.x;
    const int per   = (NNODES + 1023) / 1024;   // 147
    const int start = tid * per;
    const int end   = min(start + per, NNODES);

    int s = 0;
    for (int i = start; i < end; ++i) s += hist[i];
    tsum[tid] = s;
    __syncthreads();
    if (tid == 0) {
        int run = 0;
        for (int i = 0; i < 1024; ++i) { int t = tsum[i]; tsum[i] = run; run += t; }
    }
    __syncthreads();
    int off = tsum[tid];
    for (int i = start; i < end; ++i) {
        int h = hist[i];
        row_ptr[i] = off;
        cursor[i]  = off;
        off += h;
    }
    if (start < NNODES && end == NNODES) row_ptr[NNODES] = off;
}

__global__ __launch_bounds__(256) void scatter_kernel(
    const int* __restrict__ rows, const int* __restrict__ cols,
    const float* __restrict__ vals, int* __restrict__ cursor,
    int* __restrict__ cs, float* __restrict__ vs, int E)
{
    int i = blockIdx.x * blockDim.x + threadIdx.x;
    const int stride = gridDim.x * blockDim.x;
    for (; i < E; i += stride) {
        const int r = rows[i];
        const int pos = atomicAdd(&cursor[r], 1);
        cs[pos] = cols[i];
        vs[pos] = vals[i];
    }
}

// ---------------- fused CSR SpMM layers ----------------
// One 16-lane quarter-wave per row; lane owns 4 consecutive dims (float4).
// MODE 1: xout = s,  out = emb + coef*s
// MODE 2: xout = s,  out += coef*s
// MODE 3:            out += coef*s
template <int MODE>
__global__ __launch_bounds__(256) void csr_layer(
    const int* __restrict__ rp, const int* __restrict__ cs,
    const float* __restrict__ vs, const float* __restrict__ xin,
    float* __restrict__ xout, const float* __restrict__ emb,
    float* __restrict__ out, float coef, int nqw)
{
    const int gtid = blockIdx.x * blockDim.x + threadIdx.x;
    const int qw   = gtid >> 4;
    const int l4   = (gtid & 15) * 4;

    for (int r = qw; r < NNODES; r += nqw) {
        const int e0 = rp[r], e1 = rp[r + 1];
        float4 acc = make_float4(0.f, 0.f, 0.f, 0.f);

        int e = e0;
        for (; e + 1 < e1; e += 2) {          // 2-edge unroll for MLP
            const int   c0 = cs[e],     c1 = cs[e + 1];
            const float v0 = vs[e],     v1 = vs[e + 1];
            const float4 a0 = *reinterpret_cast<const float4*>(xin + c0 * EDIM + l4);
            const float4 a1 = *reinterpret_cast<const float4*>(xin + c1 * EDIM + l4);
            acc.x += v0 * a0.x + v1 * a1.x;
            acc.y += v0 * a0.y + v1 * a1.y;
            acc.z += v0 * a0.z + v1 * a1.z;
            acc.w += v0 * a0.w + v1 * a1.w;
        }
        if (e < e1) {
            const int   c0 = cs[e];
            const float v0 = vs[e];
            const float4 a0 = *reinterpret_cast<const float4*>(xin + c0 * EDIM + l4);
            acc.x += v0 * a0.x; acc.y += v0 * a0.y;
            acc.z += v0 * a0.z; acc.w += v0 * a0.w;
        }

        if (MODE < 3)
            *reinterpret_cast<float4*>(xout + r * EDIM + l4) = acc;

        float4 base;
        if (MODE == 1)
            base = *reinterpret_cast<const float4*>(emb + r * EDIM + l4);
        else
            base = *reinterpret_cast<const float4*>(out + r * EDIM + l4);
        float4 o;
        o.x = base.x + coef * acc.x;
        o.y = base.y + coef * acc.y;
        o.z = base.z + coef * acc.z;
        o.w = base.w + coef * acc.w;
        *reinterpret_cast<float4*>(out + r * EDIM + l4) = o;
    }
}

// ---------------- fallback: COO atomic path (small ws) ----------------

__global__ __launch_bounds__(256) void spmm_kernel(
    const int* __restrict__ rows, const int* __restrict__ cols,
    const float* __restrict__ vals, const float* __restrict__ x,
    float* __restrict__ y, int E, int nqw)
{
    const int gtid = blockIdx.x * blockDim.x + threadIdx.x;
    const int qw   = gtid >> 4;
    const int l4   = (gtid & 15) * 4;
    for (int e = qw; e < E; e += nqw) {
        const int   c = cols[e];
        const int   r = rows[e];
        const float v = vals[e];
        const float4 xv = *reinterpret_cast<const float4*>(x + c * EDIM + l4);
        float* yp = y + r * EDIM + l4;
        atomicAdd(yp + 0, xv.x * v);
        atomicAdd(yp + 1, xv.y * v);
        atomicAdd(yp + 2, xv.z * v);
        atomicAdd(yp + 3, xv.w * v);
    }
}

__global__ __launch_bounds__(256) void combine_kernel(
    const float4* __restrict__ emb, const float4* __restrict__ x,
    float c, float4* __restrict__ out, int n4)
{
    int i = blockIdx.x * blockDim.x + threadIdx.x;
    const int stride = gridDim.x * blockDim.x;
    for (; i < n4; i += stride) {
        const float4 e = emb[i], a = x[i];
        out[i] = make_float4(e.x + c * a.x, e.y + c * a.y,
                             e.z + c * a.z, e.w + c * a.w);
    }
}

__global__ __launch_bounds__(256) void accum_kernel(
    float4* __restrict__ out, const float4* __restrict__ x, float c, int n4)
{
    int i = blockIdx.x * blockDim.x + threadIdx.x;
    const int stride = gridDim.x * blockDim.x;
    for (; i < n4; i += stride) {
        const float4 o0 = out[i], a = x[i];
        out[i] = make_float4(o0.x + c * a.x, o0.y + c * a.y,
                             o0.z + c * a.z, o0.w + c * a.w);
    }
}

// ---------------- launch ----------------

extern "C" void kernel_launch(void* const* d_in, const int* in_sizes, int n_in,
                              void* d_out, int out_size, void* d_ws, size_t ws_size,
                              hipStream_t stream)
{
    const int*   rows = (const int*)  d_in[0];
    const int*   cols = (const int*)  d_in[1];
    const float* vals = (const float*)d_in[2];
    const float* emb  = (const float*)d_in[3];
    float*       out  = (float*)d_out;

    const int E  = in_sizes[0];
    const int n  = NNODES * EDIM;                  // 9,600,000 floats
    const int n4 = n / 4;
    const size_t bufBytes = (size_t)n * sizeof(float);

    // ws layout (element offsets, all 16-element aligned for float4)
    const size_t o_hist   = 0;
    const size_t o_rowptr = 150016;
    const size_t o_cursor = o_rowptr + 150016;
    const size_t o_cs     = o_cursor + 150016;
    const size_t o_vs     = o_cs + (size_t)E;
    const size_t o_x1     = o_vs + (size_t)E;
    const size_t o_x2     = o_x1 + (size_t)n;
    const size_t needCSR  = (o_x2 + (size_t)n) * 4;

    const int NQW     = 32768;                     // quarter-wave workers
    const int sblocks = NQW / 16;                  // 2048 blocks of 256

    if (ws_size >= needCSR) {
        int*   hist   = (int*)d_ws + o_hist;
        int*   rp     = (int*)d_ws + o_rowptr;
        int*   cursor = (int*)d_ws + o_cursor;
        int*   cs     = (int*)d_ws + o_cs;
        float* vs     = (float*)d_ws + o_vs;
        float* x1     = (float*)d_ws + o_x1;
        float* x2     = (float*)d_ws + o_x2;

        hipMemsetAsync(hist, 0, NNODES * sizeof(int), stream);
        hist_kernel<<<2048, 256, 0, stream>>>(rows, hist, E);
        scan_kernel<<<1, 1024, 0, stream>>>(hist, rp, cursor);
        scatter_kernel<<<2048, 256, 0, stream>>>(rows, cols, vals, cursor, cs, vs, E);

        csr_layer<1><<<sblocks, 256, 0, stream>>>(rp, cs, vs, emb, x1, emb, out, 0.5f, NQW);
        csr_layer<2><<<sblocks, 256, 0, stream>>>(rp, cs, vs, x1, x2, nullptr, out, 1.0f / 3.0f, NQW);
        csr_layer<3><<<sblocks, 256, 0, stream>>>(rp, cs, vs, x2, nullptr, nullptr, out, 0.25f, NQW);
    } else {
        // fallback: COO atomic path, 2 buffers
        float* wsA = (float*)d_ws;
        float* wsB = wsA + n;
        hipMemsetAsync(d_ws, 0, 2 * bufBytes, stream);
        spmm_kernel<<<sblocks, 256, 0, stream>>>(rows, cols, vals, emb, wsA, E, NQW);
        combine_kernel<<<2048, 256, 0, stream>>>(
            (const float4*)emb, (const float4*)wsA, 0.5f, (float4*)out, n4);
        spmm_kernel<<<sblocks, 256, 0, stream>>>(rows, cols, vals, wsA, wsB, E, NQW);
        accum_kernel<<<2048, 256, 0, stream>>>(
            (float4*)out, (const float4*)wsB, 1.0f / 3.0f, n4);
        hipMemsetAsync(wsA, 0, bufBytes, stream);
        spmm_kernel<<<sblocks, 256, 0, stream>>>(rows, cols, vals, wsB, wsA, E, NQW);
        accum_kernel<<<2048, 256, 0, stream>>>(
            (float4*)out, (const float4*)wsA, 0.25f, n4);
    }
}

// Round 5
// 1146.855 us; speedup vs baseline: 10.7167x; 1.2971x over previous
//
#include <hip/hip_runtime.h>

// LightGCN propagation on MI355X.
// out = emb + A@emb/2 + A^2@emb/3 + A^3@emb/4, A given as COO (rows, cols, vals).
// N = 150000 nodes, D = 64, E = 4.8M edges.
//
// CSR counting-sort each call, then register-accumulated CSR segment-sum
// layers (zero feature atomics). Round-5 changes vs round-4:
//  - parallel 3-pass scan (was: 1-block serial scan @ 344us)
//  - (col,val) packed to one 8B store/load (was: 2 scattered 4B stores -> 2x
//    16B write-through sectors per edge)
//  - int4/float4 edge reads in hist/scatter, 4-edge unroll in layers

#define NNODES 150000
#define EDIM   64
#define SCAN_BLK  256
#define SCAN_NBLK ((NNODES + SCAN_BLK - 1) / SCAN_BLK)   // 586

// ---------------- CSR build ----------------

__global__ __launch_bounds__(256) void hist_kernel(
    const int* __restrict__ rows, int* __restrict__ hist, int E)
{
    const int tid    = blockIdx.x * blockDim.x + threadIdx.x;
    const int stride = gridDim.x * blockDim.x;
    const int e4 = E >> 2;
    const int4* r4 = (const int4*)rows;
    for (int j = tid; j < e4; j += stride) {
        const int4 r = r4[j];
        atomicAdd(&hist[r.x], 1);
        atomicAdd(&hist[r.y], 1);
        atomicAdd(&hist[r.z], 1);
        atomicAdd(&hist[r.w], 1);
    }
    for (int j = (e4 << 2) + tid; j < E; j += stride)
        atomicAdd(&hist[rows[j]], 1);
}

// pass 1: per-block exclusive scan; local prefix -> row_ptr, block sum -> bsums
__global__ __launch_bounds__(SCAN_BLK) void scan1_kernel(
    const int* __restrict__ hist, int* __restrict__ row_ptr,
    int* __restrict__ bsums)
{
    __shared__ int sh[SCAN_BLK];
    const int tid = threadIdx.x;
    const int i   = blockIdx.x * SCAN_BLK + tid;
    const int v   = (i < NNODES) ? hist[i] : 0;
    sh[tid] = v;
    __syncthreads();
    for (int off = 1; off < SCAN_BLK; off <<= 1) {
        const int t = (tid >= off) ? sh[tid - off] : 0;
        __syncthreads();
        sh[tid] += t;
        __syncthreads();
    }
    if (i < NNODES) row_ptr[i] = sh[tid] - v;        // local exclusive
    if (tid == SCAN_BLK - 1) bsums[blockIdx.x] = sh[tid];
}

// pass 2: one block scans the 586 block sums -> exclusive block offsets
__global__ __launch_bounds__(1024) void scan2_kernel(int* __restrict__ bsums)
{
    __shared__ int sh[1024];
    const int tid = threadIdx.x;
    const int v   = (tid < SCAN_NBLK) ? bsums[tid] : 0;
    sh[tid] = v;
    __syncthreads();
    for (int off = 1; off < 1024; off <<= 1) {
        const int t = (tid >= off) ? sh[tid - off] : 0;
        __syncthreads();
        sh[tid] += t;
        __syncthreads();
    }
    if (tid < SCAN_NBLK) bsums[tid] = sh[tid] - v;   // exclusive
}

// pass 3: row_ptr[i] += block offset; copy to cursor; write sentinel
__global__ __launch_bounds__(SCAN_BLK) void scan3_kernel(
    int* __restrict__ row_ptr, const int* __restrict__ bsums,
    int* __restrict__ cursor, int E)
{
    const int i = blockIdx.x * SCAN_BLK + threadIdx.x;
    if (i < NNODES) {
        const int o = row_ptr[i] + bsums[blockIdx.x];
        row_ptr[i] = o;
        cursor[i]  = o;
    }
    if (i == 0) row_ptr[NNODES] = E;
}

// scatter: one packed 8B (col,val) store per edge
__global__ __launch_bounds__(256) void scatter_kernel(
    const int* __restrict__ rows, const int* __restrict__ cols,
    const float* __restrict__ vals, int* __restrict__ cursor,
    unsigned long long* __restrict__ cvs, int E)
{
    const int tid    = blockIdx.x * blockDim.x + threadIdx.x;
    const int stride = gridDim.x * blockDim.x;
    const int e4 = E >> 2;
    const int4*   r4 = (const int4*)rows;
    const int4*   c4 = (const int4*)cols;
    const float4* v4 = (const float4*)vals;
    for (int j = tid; j < e4; j += stride) {
        const int4   r = r4[j];
        const int4   c = c4[j];
        const float4 v = v4[j];
        int p;
        p = atomicAdd(&cursor[r.x], 1);
        cvs[p] = ((unsigned long long)__float_as_uint(v.x) << 32) | (unsigned)c.x;
        p = atomicAdd(&cursor[r.y], 1);
        cvs[p] = ((unsigned long long)__float_as_uint(v.y) << 32) | (unsigned)c.y;
        p = atomicAdd(&cursor[r.z], 1);
        cvs[p] = ((unsigned long long)__float_as_uint(v.z) << 32) | (unsigned)c.z;
        p = atomicAdd(&cursor[r.w], 1);
        cvs[p] = ((unsigned long long)__float_as_uint(v.w) << 32) | (unsigned)c.w;
    }
    for (int j = (e4 << 2) + tid; j < E; j += stride) {
        const int p = atomicAdd(&cursor[rows[j]], 1);
        cvs[p] = ((unsigned long long)__float_as_uint(vals[j]) << 32) | (unsigned)cols[j];
    }
}

// ---------------- fused CSR SpMM layers ----------------
// One 16-lane quarter-wave per row; lane owns 4 consecutive dims (float4).
// MODE 1: xout = s,  out = emb + coef*s
// MODE 2: xout = s,  out += coef*s
// MODE 3:            out += coef*s
template <int MODE>
__global__ __launch_bounds__(256) void csr_layer(
    const int* __restrict__ rp, const unsigned long long* __restrict__ cvs,
    const float* __restrict__ xin, float* __restrict__ xout,
    const float* __restrict__ emb, float* __restrict__ out,
    float coef, int nqw)
{
    const int gtid = blockIdx.x * blockDim.x + threadIdx.x;
    const int qw   = gtid >> 4;
    const int l4   = (gtid & 15) * 4;

    for (int r = qw; r < NNODES; r += nqw) {
        const int e0 = rp[r], e1 = rp[r + 1];
        float4 acc = make_float4(0.f, 0.f, 0.f, 0.f);

        int e = e0;
        for (; e + 3 < e1; e += 4) {          // 4 independent 256B gathers
            const unsigned long long u0 = cvs[e],     u1 = cvs[e + 1];
            const unsigned long long u2 = cvs[e + 2], u3 = cvs[e + 3];
            const float4 a0 = *reinterpret_cast<const float4*>(xin + (unsigned)(u0 & 0xffffffffu) * EDIM + l4);
            const float4 a1 = *reinterpret_cast<const float4*>(xin + (unsigned)(u1 & 0xffffffffu) * EDIM + l4);
            const float4 a2 = *reinterpret_cast<const float4*>(xin + (unsigned)(u2 & 0xffffffffu) * EDIM + l4);
            const float4 a3 = *reinterpret_cast<const float4*>(xin + (unsigned)(u3 & 0xffffffffu) * EDIM + l4);
            const float v0 = __uint_as_float((unsigned)(u0 >> 32));
            const float v1 = __uint_as_float((unsigned)(u1 >> 32));
            const float v2 = __uint_as_float((unsigned)(u2 >> 32));
            const float v3 = __uint_as_float((unsigned)(u3 >> 32));
            acc.x += v0 * a0.x + v1 * a1.x + v2 * a2.x + v3 * a3.x;
            acc.y += v0 * a0.y + v1 * a1.y + v2 * a2.y + v3 * a3.y;
            acc.z += v0 * a0.z + v1 * a1.z + v2 * a2.z + v3 * a3.z;
            acc.w += v0 * a0.w + v1 * a1.w + v2 * a2.w + v3 * a3.w;
        }
        for (; e < e1; ++e) {
            const unsigned long long u0 = cvs[e];
            const float4 a0 = *reinterpret_cast<const float4*>(xin + (unsigned)(u0 & 0xffffffffu) * EDIM + l4);
            const float v0 = __uint_as_float((unsigned)(u0 >> 32));
            acc.x += v0 * a0.x; acc.y += v0 * a0.y;
            acc.z += v0 * a0.z; acc.w += v0 * a0.w;
        }

        if (MODE < 3)
            *reinterpret_cast<float4*>(xout + r * EDIM + l4) = acc;

        float4 base;
        if (MODE == 1)
            base = *reinterpret_cast<const float4*>(emb + r * EDIM + l4);
        else
            base = *reinterpret_cast<const float4*>(out + r * EDIM + l4);
        float4 o;
        o.x = base.x + coef * acc.x;
        o.y = base.y + coef * acc.y;
        o.z = base.z + coef * acc.z;
        o.w = base.w + coef * acc.w;
        *reinterpret_cast<float4*>(out + r * EDIM + l4) = o;
    }
}

// ---------------- fallback: COO atomic path (small ws) ----------------

__global__ __launch_bounds__(256) void spmm_kernel(
    const int* __restrict__ rows, const int* __restrict__ cols,
    const float* __restrict__ vals, const float* __restrict__ x,
    float* __restrict__ y, int E, int nqw)
{
    const int gtid = blockIdx.x * blockDim.x + threadIdx.x;
    const int qw   = gtid >> 4;
    const int l4   = (gtid & 15) * 4;
    for (int e = qw; e < E; e += nqw) {
        const int   c = cols[e];
        const int   r = rows[e];
        const float v = vals[e];
        const float4 xv = *reinterpret_cast<const float4*>(x + c * EDIM + l4);
        float* yp = y + r * EDIM + l4;
        atomicAdd(yp + 0, xv.x * v);
        atomicAdd(yp + 1, xv.y * v);
        atomicAdd(yp + 2, xv.z * v);
        atomicAdd(yp + 3, xv.w * v);
    }
}

__global__ __launch_bounds__(256) void combine_kernel(
    const float4* __restrict__ emb, const float4* __restrict__ x,
    float c, float4* __restrict__ out, int n4)
{
    int i = blockIdx.x * blockDim.x + threadIdx.x;
    const int stride = gridDim.x * blockDim.x;
    for (; i < n4; i += stride) {
        const float4 e = emb[i], a = x[i];
        out[i] = make_float4(e.x + c * a.x, e.y + c * a.y,
                             e.z + c * a.z, e.w + c * a.w);
    }
}

__global__ __launch_bounds__(256) void accum_kernel(
    float4* __restrict__ out, const float4* __restrict__ x, float c, int n4)
{
    int i = blockIdx.x * blockDim.x + threadIdx.x;
    const int stride = gridDim.x * blockDim.x;
    for (; i < n4; i += stride) {
        const float4 o0 = out[i], a = x[i];
        out[i] = make_float4(o0.x + c * a.x, o0.y + c * a.y,
                             o0.z + c * a.z, o0.w + c * a.w);
    }
}

// ---------------- launch ----------------

extern "C" void kernel_launch(void* const* d_in, const int* in_sizes, int n_in,
                              void* d_out, int out_size, void* d_ws, size_t ws_size,
                              hipStream_t stream)
{
    const int*   rows = (const int*)  d_in[0];
    const int*   cols = (const int*)  d_in[1];
    const float* vals = (const float*)d_in[2];
    const float* emb  = (const float*)d_in[3];
    float*       out  = (float*)d_out;

    const int E  = in_sizes[0];
    const int n  = NNODES * EDIM;                  // 9,600,000 floats
    const int n4 = n / 4;
    const size_t bufBytes = (size_t)n * sizeof(float);

    // ws layout (4-byte element offsets; cvs needs 8B alignment -> even offsets)
    const size_t o_hist   = 0;
    const size_t o_rowptr = 150016;
    const size_t o_cursor = o_rowptr + 150016;
    const size_t o_cvs    = o_cursor + 150016;     // 2*E units (8B per edge)
    const size_t o_x1     = o_cvs + 2 * (size_t)E;
    const size_t o_x2     = o_x1 + (size_t)n;
    const size_t needCSR  = (o_x2 + (size_t)n) * 4;

    const int NQW     = 32768;                     // quarter-wave workers
    const int sblocks = NQW / 16;                  // 2048 blocks of 256

    if (ws_size >= needCSR) {
        int*   hist   = (int*)d_ws + o_hist;
        int*   rp     = (int*)d_ws + o_rowptr;
        int*   cursor = (int*)d_ws + o_cursor;
        unsigned long long* cvs = (unsigned long long*)((int*)d_ws + o_cvs);
        float* x1     = (float*)d_ws + o_x1;
        float* x2     = (float*)d_ws + o_x2;
        int*   bsums  = (int*)x1;                  // dead until layer 1 runs

        hipMemsetAsync(hist, 0, NNODES * sizeof(int), stream);
        hist_kernel<<<2048, 256, 0, stream>>>(rows, hist, E);
        scan1_kernel<<<SCAN_NBLK, SCAN_BLK, 0, stream>>>(hist, rp, bsums);
        scan2_kernel<<<1, 1024, 0, stream>>>(bsums);
        scan3_kernel<<<SCAN_NBLK, SCAN_BLK, 0, stream>>>(rp, bsums, cursor, E);
        scatter_kernel<<<2048, 256, 0, stream>>>(rows, cols, vals, cursor, cvs, E);

        csr_layer<1><<<sblocks, 256, 0, stream>>>(rp, cvs, emb, x1, emb, out, 0.5f, NQW);
        csr_layer<2><<<sblocks, 256, 0, stream>>>(rp, cvs, x1, x2, nullptr, out, 1.0f / 3.0f, NQW);
        csr_layer<3><<<sblocks, 256, 0, stream>>>(rp, cvs, x2, nullptr, nullptr, out, 0.25f, NQW);
    } else {
        // fallback: COO atomic path, 2 buffers
        float* wsA = (float*)d_ws;
        float* wsB = wsA + n;
        hipMemsetAsync(d_ws, 0, 2 * bufBytes, stream);
        spmm_kernel<<<sblocks, 256, 0, stream>>>(rows, cols, vals, emb, wsA, E, NQW);
        combine_kernel<<<2048, 256, 0, stream>>>(
            (const float4*)emb, (const float4*)wsA, 0.5f, (float4*)out, n4);
        spmm_kernel<<<sblocks, 256, 0, stream>>>(rows, cols, vals, wsA, wsB, E, NQW);
        accum_kernel<<<2048, 256, 0, stream>>>(
            (float4*)out, (const float4*)wsB, 1.0f / 3.0f, n4);
        hipMemsetAsync(wsA, 0, bufBytes, stream);
        spmm_kernel<<<sblocks, 256, 0, stream>>>(rows, cols, vals, wsB, wsA, E, NQW);
        accum_kernel<<<2048, 256, 0, stream>>>(
            (float4*)out, (const float4*)wsA, 0.25f, n4);
    }
}

// Round 6
// 1015.504 us; speedup vs baseline: 12.1029x; 1.1293x over previous
//
#include <hip/hip_runtime.h>

// LightGCN propagation on MI355X.
// out = emb + A@emb/2 + A^2@emb/3 + A^3@emb/4, A given as COO (rows, cols, vals).
// N = 150000 nodes, D = 64, E = 4.8M edges.
//
// Round-6 build pipeline (replaces hist+scan+scatter):
//   bcount (LDS-aggregated bucket histogram, 64B-padded global counters)
//   bscan  (1-block scan of 1172 bucket counts)
//   append (edge -> bucket tail, atomic cursor per 64B line; writes cluster
//           around 1172 hot tails so L2 merges -> ~logical write traffic)
//   bsort  (per-bucket LDS counting sort -> sequential CSR writes + rp[])
// Layers: register-accumulated CSR segment-sum, fused output accumulation.

#define NNODES 150000
#define EDIM   64
#define BROWS  128
#define NBUCK  ((NNODES + BROWS - 1) / BROWS)   // 1172
#define BCAP   6144                              // mean 4096, ~32 sigma headroom
#define CPAD   16                                // ints per counter (64B line)

// ---------------- bucket build ----------------

__global__ __launch_bounds__(256) void bcount_kernel(
    const int* __restrict__ rows, int* __restrict__ bcnt_pad, int E)
{
    __shared__ int lh[NBUCK];
    for (int i = threadIdx.x; i < NBUCK; i += 256) lh[i] = 0;
    __syncthreads();

    const int tid    = blockIdx.x * blockDim.x + threadIdx.x;
    const int stride = gridDim.x * blockDim.x;
    const int e4 = E >> 2;
    const int4* r4 = (const int4*)rows;
    for (int j = tid; j < e4; j += stride) {
        const int4 r = r4[j];
        atomicAdd(&lh[r.x >> 7], 1);
        atomicAdd(&lh[r.y >> 7], 1);
        atomicAdd(&lh[r.z >> 7], 1);
        atomicAdd(&lh[r.w >> 7], 1);
    }
    for (int j = (e4 << 2) + tid; j < E; j += stride)
        atomicAdd(&lh[rows[j] >> 7], 1);
    __syncthreads();

    for (int i = threadIdx.x; i < NBUCK; i += 256) {
        const int c = lh[i];
        if (c) atomicAdd(&bcnt_pad[i * CPAD], c);
    }
}

// one block: exclusive scan of 1172 bucket counts -> bbase (+sentinel), bcur
__global__ __launch_bounds__(1024) void bscan_kernel(
    const int* __restrict__ bcnt_pad, int* __restrict__ bbase,
    int* __restrict__ bcur_pad, int E)
{
    __shared__ int sh[2048];
    const int t = threadIdx.x;
    const int v0 = (t < NBUCK) ? bcnt_pad[t * CPAD] : 0;
    const int v1 = (t + 1024 < NBUCK) ? bcnt_pad[(t + 1024) * CPAD] : 0;
    sh[t] = v0; sh[t + 1024] = v1;
    __syncthreads();
    for (int off = 1; off < 2048; off <<= 1) {
        const int a = (t >= off) ? sh[t - off] : 0;
        const int b = (t + 1024 >= off) ? sh[t + 1024 - off] : 0;
        __syncthreads();
        sh[t] += a; sh[t + 1024] += b;
        __syncthreads();
    }
    if (t < NBUCK) {
        const int e = sh[t] - v0;                 // exclusive
        bbase[t] = e;
        bcur_pad[t * CPAD] = e;
    }
    if (t + 1024 < NBUCK) {
        const int e = sh[t + 1024] - v1;
        bbase[t + 1024] = e;
        bcur_pad[(t + 1024) * CPAD] = e;
    }
    if (t == 0) bbase[NBUCK] = E;
}

// append edges to bucket regions; staged record packs (val | col | lrow)
__global__ __launch_bounds__(256) void append_kernel(
    const int* __restrict__ rows, const int* __restrict__ cols,
    const float* __restrict__ vals, int* __restrict__ bcur_pad,
    unsigned long long* __restrict__ staged, int E)
{
    const int tid    = blockIdx.x * blockDim.x + threadIdx.x;
    const int stride = gridDim.x * blockDim.x;
    const int e4 = E >> 2;
    const int4*   r4 = (const int4*)rows;
    const int4*   c4 = (const int4*)cols;
    const float4* v4 = (const float4*)vals;

    #define APP1(RR, CC, VV) {                                             \
        const int b_  = (RR) >> 7;                                         \
        const int lr_ = (RR) & 127;                                        \
        const int p_  = atomicAdd(&bcur_pad[b_ * CPAD], 1);                \
        staged[p_] = ((unsigned long long)__float_as_uint(VV) << 32) |     \
                     (unsigned)((CC) | (lr_ << 18)); }

    for (int j = tid; j < e4; j += stride) {
        const int4   r = r4[j];
        const int4   c = c4[j];
        const float4 v = v4[j];
        APP1(r.x, c.x, v.x)
        APP1(r.y, c.y, v.y)
        APP1(r.z, c.z, v.z)
        APP1(r.w, c.w, v.w)
    }
    for (int j = (e4 << 2) + tid; j < E; j += stride)
        APP1(rows[j], cols[j], vals[j])
    #undef APP1
}

// per-bucket LDS counting sort -> sequential cvs writes + rp[]
__global__ __launch_bounds__(256) void bsort_kernel(
    const int* __restrict__ bbase, const unsigned long long* __restrict__ staged,
    unsigned long long* __restrict__ cvs, int* __restrict__ rp, int E)
{
    __shared__ unsigned long long sbuf[BCAP];   // 48 KB
    __shared__ int lhist[BROWS];
    __shared__ int lcur[BROWS];

    const int b    = blockIdx.x;
    const int base = bbase[b];
    int cnt = bbase[b + 1] - base;
    if (cnt > BCAP) cnt = BCAP;                 // safety clamp (never expected)
    const int t = threadIdx.x;

    if (t < BROWS) lhist[t] = 0;
    __syncthreads();

    // phase A: local histogram over lrow
    for (int i = t; i < cnt; i += 256) {
        const unsigned lo = (unsigned)(staged[base + i] & 0xffffffffu);
        atomicAdd(&lhist[(lo >> 18) & 127], 1);
    }
    __syncthreads();

    // phase B: exclusive scan of 128 counts (Hillis-Steele, full-block barriers)
    if (t < BROWS) lcur[t] = lhist[t];
    __syncthreads();
    for (int off = 1; off < BROWS; off <<= 1) {
        int a = 0;
        if (t < BROWS && t >= off) a = lcur[t - off];
        __syncthreads();
        if (t < BROWS) lcur[t] += a;
        __syncthreads();
    }
    int excl = 0;
    if (t < BROWS) excl = lcur[t] - lhist[t];
    __syncthreads();
    if (t < BROWS) lcur[t] = excl;
    const int grow = b * BROWS + t;
    if (t < BROWS && grow < NNODES) rp[grow] = base + excl;
    if (b == 0 && t == 0) rp[NNODES] = E;
    __syncthreads();

    // phase C: place sorted into LDS (strip lrow, keep 18-bit col)
    for (int i = t; i < cnt; i += 256) {
        const unsigned long long u = staged[base + i];
        const unsigned lo = (unsigned)(u & 0xffffffffu);
        const int lr  = (lo >> 18) & 127;
        const int pos = atomicAdd(&lcur[lr], 1);
        sbuf[pos] = (u & 0xffffffff00000000ull) | (lo & 0x3ffffu);
    }
    __syncthreads();

    // phase D: sequential coalesced global write
    for (int i = t; i < cnt; i += 256) cvs[base + i] = sbuf[i];
}

// ---------------- fused CSR SpMM layers ----------------
// One 16-lane quarter-wave per row; lane owns 4 consecutive dims (float4).
// MODE 1: xout = s,  out = emb + coef*s
// MODE 2: xout = s,  out += coef*s
// MODE 3:            out += coef*s
template <int MODE>
__global__ __launch_bounds__(256) void csr_layer(
    const int* __restrict__ rp, const unsigned long long* __restrict__ cvs,
    const float* __restrict__ xin, float* __restrict__ xout,
    const float* __restrict__ emb, float* __restrict__ out,
    float coef, int nqw)
{
    const int gtid = blockIdx.x * blockDim.x + threadIdx.x;
    const int qw   = gtid >> 4;
    const int l4   = (gtid & 15) * 4;

    for (int r = qw; r < NNODES; r += nqw) {
        const int e0 = rp[r], e1 = rp[r + 1];
        float4 acc = make_float4(0.f, 0.f, 0.f, 0.f);

        int e = e0;
        for (; e + 3 < e1; e += 4) {          // 4 independent 256B gathers
            const unsigned long long u0 = cvs[e],     u1 = cvs[e + 1];
            const unsigned long long u2 = cvs[e + 2], u3 = cvs[e + 3];
            const float4 a0 = *reinterpret_cast<const float4*>(xin + (unsigned)(u0 & 0xffffffffu) * EDIM + l4);
            const float4 a1 = *reinterpret_cast<const float4*>(xin + (unsigned)(u1 & 0xffffffffu) * EDIM + l4);
            const float4 a2 = *reinterpret_cast<const float4*>(xin + (unsigned)(u2 & 0xffffffffu) * EDIM + l4);
            const float4 a3 = *reinterpret_cast<const float4*>(xin + (unsigned)(u3 & 0xffffffffu) * EDIM + l4);
            const float v0 = __uint_as_float((unsigned)(u0 >> 32));
            const float v1 = __uint_as_float((unsigned)(u1 >> 32));
            const float v2 = __uint_as_float((unsigned)(u2 >> 32));
            const float v3 = __uint_as_float((unsigned)(u3 >> 32));
            acc.x += v0 * a0.x + v1 * a1.x + v2 * a2.x + v3 * a3.x;
            acc.y += v0 * a0.y + v1 * a1.y + v2 * a2.y + v3 * a3.y;
            acc.z += v0 * a0.z + v1 * a1.z + v2 * a2.z + v3 * a3.z;
            acc.w += v0 * a0.w + v1 * a1.w + v2 * a2.w + v3 * a3.w;
        }
        for (; e < e1; ++e) {
            const unsigned long long u0 = cvs[e];
            const float4 a0 = *reinterpret_cast<const float4*>(xin + (unsigned)(u0 & 0xffffffffu) * EDIM + l4);
            const float v0 = __uint_as_float((unsigned)(u0 >> 32));
            acc.x += v0 * a0.x; acc.y += v0 * a0.y;
            acc.z += v0 * a0.z; acc.w += v0 * a0.w;
        }

        if (MODE < 3)
            *reinterpret_cast<float4*>(xout + r * EDIM + l4) = acc;

        float4 base;
        if (MODE == 1)
            base = *reinterpret_cast<const float4*>(emb + r * EDIM + l4);
        else
            base = *reinterpret_cast<const float4*>(out + r * EDIM + l4);
        float4 o;
        o.x = base.x + coef * acc.x;
        o.y = base.y + coef * acc.y;
        o.z = base.z + coef * acc.z;
        o.w = base.w + coef * acc.w;
        *reinterpret_cast<float4*>(out + r * EDIM + l4) = o;
    }
}

// ---------------- fallback: COO atomic path (small ws) ----------------

__global__ __launch_bounds__(256) void spmm_kernel(
    const int* __restrict__ rows, const int* __restrict__ cols,
    const float* __restrict__ vals, const float* __restrict__ x,
    float* __restrict__ y, int E, int nqw)
{
    const int gtid = blockIdx.x * blockDim.x + threadIdx.x;
    const int qw   = gtid >> 4;
    const int l4   = (gtid & 15) * 4;
    for (int e = qw; e < E; e += nqw) {
        const int   c = cols[e];
        const int   r = rows[e];
        const float v = vals[e];
        const float4 xv = *reinterpret_cast<const float4*>(x + c * EDIM + l4);
        float* yp = y + r * EDIM + l4;
        atomicAdd(yp + 0, xv.x * v);
        atomicAdd(yp + 1, xv.y * v);
        atomicAdd(yp + 2, xv.z * v);
        atomicAdd(yp + 3, xv.w * v);
    }
}

__global__ __launch_bounds__(256) void combine_kernel(
    const float4* __restrict__ emb, const float4* __restrict__ x,
    float c, float4* __restrict__ out, int n4)
{
    int i = blockIdx.x * blockDim.x + threadIdx.x;
    const int stride = gridDim.x * blockDim.x;
    for (; i < n4; i += stride) {
        const float4 e = emb[i], a = x[i];
        out[i] = make_float4(e.x + c * a.x, e.y + c * a.y,
                             e.z + c * a.z, e.w + c * a.w);
    }
}

__global__ __launch_bounds__(256) void accum_kernel(
    float4* __restrict__ out, const float4* __restrict__ x, float c, int n4)
{
    int i = blockIdx.x * blockDim.x + threadIdx.x;
    const int stride = gridDim.x * blockDim.x;
    for (; i < n4; i += stride) {
        const float4 o0 = out[i], a = x[i];
        out[i] = make_float4(o0.x + c * a.x, o0.y + c * a.y,
                             o0.z + c * a.z, o0.w + c * a.w);
    }
}

// ---------------- launch ----------------

extern "C" void kernel_launch(void* const* d_in, const int* in_sizes, int n_in,
                              void* d_out, int out_size, void* d_ws, size_t ws_size,
                              hipStream_t stream)
{
    const int*   rows = (const int*)  d_in[0];
    const int*   cols = (const int*)  d_in[1];
    const float* vals = (const float*)d_in[2];
    const float* emb  = (const float*)d_in[3];
    float*       out  = (float*)d_out;

    const int E  = in_sizes[0];
    const int n  = NNODES * EDIM;                  // 9,600,000 floats
    const int n4 = n / 4;
    const size_t bufBytes = (size_t)n * sizeof(float);

    // ws layout (4-byte units; 8B-aligned offsets are even)
    const size_t o_bcnt   = 0;                         // NBUCK*CPAD = 18752
    const size_t o_bcur   = o_bcnt + (size_t)NBUCK * CPAD;
    const size_t o_bbase  = o_bcur + (size_t)NBUCK * CPAD;
    const size_t o_rp     = o_bbase + 1184;            // NBUCK+1 rounded up
    const size_t o_cvs    = o_rp + 150016;             // even
    const size_t o_x1     = o_cvs + 2 * (size_t)E;
    const size_t o_staged = o_x1 + (size_t)n;          // x2 aliases staged
    const size_t needCSR  = (o_staged + 2 * (size_t)E) * 4;

    const int NQW     = 32768;                     // quarter-wave workers
    const int sblocks = NQW / 16;                  // 2048 blocks of 256

    if (ws_size >= needCSR) {
        int* bcnt  = (int*)d_ws + o_bcnt;
        int* bcur  = (int*)d_ws + o_bcur;
        int* bbase = (int*)d_ws + o_bbase;
        int* rp    = (int*)d_ws + o_rp;
        unsigned long long* cvs    = (unsigned long long*)((int*)d_ws + o_cvs);
        float*              x1     = (float*)d_ws + o_x1;
        unsigned long long* staged = (unsigned long long*)((int*)d_ws + o_staged);
        float*              x2     = (float*)staged;   // alias: staged dead after bsort

        hipMemsetAsync(bcnt, 0, (size_t)NBUCK * CPAD * sizeof(int), stream);
        bcount_kernel<<<512, 256, 0, stream>>>(rows, bcnt, E);
        bscan_kernel<<<1, 1024, 0, stream>>>(bcnt, bbase, bcur, E);
        append_kernel<<<2048, 256, 0, stream>>>(rows, cols, vals, bcur, staged, E);
        bsort_kernel<<<NBUCK, 256, 0, stream>>>(bbase, staged, cvs, rp, E);

        csr_layer<1><<<sblocks, 256, 0, stream>>>(rp, cvs, emb, x1, emb, out, 0.5f, NQW);
        csr_layer<2><<<sblocks, 256, 0, stream>>>(rp, cvs, x1, x2, nullptr, out, 1.0f / 3.0f, NQW);
        csr_layer<3><<<sblocks, 256, 0, stream>>>(rp, cvs, x2, nullptr, nullptr, out, 0.25f, NQW);
    } else {
        // fallback: COO atomic path, 2 buffers
        float* wsA = (float*)d_ws;
        float* wsB = wsA + n;
        hipMemsetAsync(d_ws, 0, 2 * bufBytes, stream);
        spmm_kernel<<<sblocks, 256, 0, stream>>>(rows, cols, vals, emb, wsA, E, NQW);
        combine_kernel<<<2048, 256, 0, stream>>>(
            (const float4*)emb, (const float4*)wsA, 0.5f, (float4*)out, n4);
        spmm_kernel<<<sblocks, 256, 0, stream>>>(rows, cols, vals, wsA, wsB, E, NQW);
        accum_kernel<<<2048, 256, 0, stream>>>(
            (float4*)out, (const float4*)wsB, 1.0f / 3.0f, n4);
        hipMemsetAsync(wsA, 0, bufBytes, stream);
        spmm_kernel<<<sblocks, 256, 0, stream>>>(rows, cols, vals, wsB, wsA, E, NQW);
        accum_kernel<<<2048, 256, 0, stream>>>(
            (float4*)out, (const float4*)wsA, 0.25f, n4);
    }
}

// Round 7
// 825.180 us; speedup vs baseline: 14.8944x; 1.2306x over previous
//
#include <hip/hip_runtime.h>

// LightGCN propagation on MI355X.
// out = emb + A@emb/2 + A^2@emb/3 + A^3@emb/4, A given as COO (rows, cols, vals).
// N = 150000 nodes, D = 64, E = 4.8M edges.
//
// Round-7 build pipeline: radix-partition with BLOCK-PRIVATE output runs.
// (Round-6 shared bucket tails: lines filled by stores from 8 XCDs -> line
// bounce -> 274MB HBM writes. Private (block,bucket) runs keep each 64B line
// fed by ONE block -> L2-resident until full -> ~logical write traffic.)
//   pcount: per-block histogram of its contiguous edge range -> gcnt[b][k]
//   pscan1: scan gcnt over blocks per bucket -> private run offsets + btot
//   bscan : exclusive scan of bucket totals -> bbase
//   pplace: LDS cursors from bbase+gcnt; direct stores to private runs
//   bsort : per-bucket LDS counting sort -> sequential CSR writes + rp[]
// Layers: register-accumulated CSR segment-sum, fused output accumulation.

#define NNODES 150000
#define EDIM   64
#define BROWS  128
#define NBUCK  ((NNODES + BROWS - 1) / BROWS)   // 1172
#define BCAP   6144                              // mean 4096, ~32 sigma headroom
#define NB     128                               // partition blocks

// ---------------- partition build ----------------

// block b histograms its contiguous range -> gcnt[b*NBUCK + k] (coalesced)
__global__ __launch_bounds__(256) void pcount_kernel(
    const int* __restrict__ rows, int* __restrict__ gcnt, int E, int per)
{
    __shared__ int lh[NBUCK];
    for (int i = threadIdx.x; i < NBUCK; i += 256) lh[i] = 0;
    __syncthreads();

    const int start = blockIdx.x * per;
    int end = start + per; if (end > E) end = E;
    const int vend = start + (((end - start) >> 2) << 2);

    const int4* r4 = (const int4*)(rows + start);
    const int nv = (vend - start) >> 2;
    for (int j = threadIdx.x; j < nv; j += 256) {
        const int4 r = r4[j];
        atomicAdd(&lh[r.x >> 7], 1);
        atomicAdd(&lh[r.y >> 7], 1);
        atomicAdd(&lh[r.z >> 7], 1);
        atomicAdd(&lh[r.w >> 7], 1);
    }
    for (int j = vend + threadIdx.x; j < end; j += 256)
        atomicAdd(&lh[rows[j] >> 7], 1);
    __syncthreads();

    int* g = gcnt + blockIdx.x * NBUCK;
    for (int i = threadIdx.x; i < NBUCK; i += 256) g[i] = lh[i];
}

// per-bucket serial scan over the NB block counts (coalesced across threads)
__global__ __launch_bounds__(256) void pscan1_kernel(
    int* __restrict__ gcnt, int* __restrict__ btot)
{
    const int k = blockIdx.x * blockDim.x + threadIdx.x;
    if (k >= NBUCK) return;
    int run = 0;
    for (int c = 0; c < NB; c += 32) {
        int v[32];
        #pragma unroll
        for (int j = 0; j < 32; ++j) v[j] = gcnt[(c + j) * NBUCK + k];
        #pragma unroll
        for (int j = 0; j < 32; ++j) {
            const int t = v[j];
            gcnt[(c + j) * NBUCK + k] = run;   // exclusive within bucket
            run += t;
        }
    }
    btot[k] = run;
}

// one block: exclusive scan of 1172 bucket totals -> bbase (+sentinel)
__global__ __launch_bounds__(1024) void bscan_kernel(
    const int* __restrict__ btot, int* __restrict__ bbase, int E)
{
    __shared__ int sh[2048];
    const int t = threadIdx.x;
    const int v0 = (t < NBUCK) ? btot[t] : 0;
    const int v1 = (t + 1024 < NBUCK) ? btot[t + 1024] : 0;
    sh[t] = v0; sh[t + 1024] = v1;
    __syncthreads();
    for (int off = 1; off < 2048; off <<= 1) {
        const int a = (t >= off) ? sh[t - off] : 0;
        const int b = (t + 1024 >= off) ? sh[t + 1024 - off] : 0;
        __syncthreads();
        sh[t] += a; sh[t + 1024] += b;
        __syncthreads();
    }
    if (t < NBUCK)        bbase[t]        = sh[t] - v0;
    if (t + 1024 < NBUCK) bbase[t + 1024] = sh[t + 1024] - v1;
    if (t == 0) bbase[NBUCK] = E;
}

// block b places its range into its PRIVATE (block,bucket) runs
__global__ __launch_bounds__(256) void pplace_kernel(
    const int* __restrict__ rows, const int* __restrict__ cols,
    const float* __restrict__ vals, const int* __restrict__ gcnt,
    const int* __restrict__ bbase, unsigned long long* __restrict__ staged,
    int E, int per)
{
    __shared__ int lcur[NBUCK];
    const int* g = gcnt + blockIdx.x * NBUCK;
    for (int i = threadIdx.x; i < NBUCK; i += 256)
        lcur[i] = bbase[i] + g[i];
    __syncthreads();

    const int start = blockIdx.x * per;
    int end = start + per; if (end > E) end = E;
    const int vend = start + (((end - start) >> 2) << 2);

    #define PL1(RR, CC, VV) {                                              \
        const int b_  = (RR) >> 7;                                         \
        const int lr_ = (RR) & 127;                                        \
        const int p_  = atomicAdd(&lcur[b_], 1);                           \
        staged[p_] = ((unsigned long long)__float_as_uint(VV) << 32) |     \
                     (unsigned)((CC) | (lr_ << 18)); }

    const int4*   r4 = (const int4*)(rows + start);
    const int4*   c4 = (const int4*)(cols + start);
    const float4* v4 = (const float4*)(vals + start);
    const int nv = (vend - start) >> 2;
    for (int j = threadIdx.x; j < nv; j += 256) {
        const int4   r = r4[j];
        const int4   c = c4[j];
        const float4 v = v4[j];
        PL1(r.x, c.x, v.x)
        PL1(r.y, c.y, v.y)
        PL1(r.z, c.z, v.z)
        PL1(r.w, c.w, v.w)
    }
    for (int j = vend + threadIdx.x; j < end; j += 256)
        PL1(rows[j], cols[j], vals[j])
    #undef PL1
}

// per-bucket LDS counting sort -> sequential cvs writes + rp[]
__global__ __launch_bounds__(256) void bsort_kernel(
    const int* __restrict__ bbase, const unsigned long long* __restrict__ staged,
    unsigned long long* __restrict__ cvs, int* __restrict__ rp, int E)
{
    __shared__ unsigned long long sbuf[BCAP];   // 48 KB
    __shared__ int lhist[BROWS];
    __shared__ int lcur[BROWS];

    const int b    = blockIdx.x;
    const int base = bbase[b];
    int cnt = bbase[b + 1] - base;
    if (cnt > BCAP) cnt = BCAP;                 // safety clamp (never expected)
    const int t = threadIdx.x;

    if (t < BROWS) lhist[t] = 0;
    __syncthreads();

    // phase A: local histogram over lrow
    for (int i = t; i < cnt; i += 256) {
        const unsigned lo = (unsigned)(staged[base + i] & 0xffffffffu);
        atomicAdd(&lhist[(lo >> 18) & 127], 1);
    }
    __syncthreads();

    // phase B: exclusive scan of 128 counts
    if (t < BROWS) lcur[t] = lhist[t];
    __syncthreads();
    for (int off = 1; off < BROWS; off <<= 1) {
        int a = 0;
        if (t < BROWS && t >= off) a = lcur[t - off];
        __syncthreads();
        if (t < BROWS) lcur[t] += a;
        __syncthreads();
    }
    int excl = 0;
    if (t < BROWS) excl = lcur[t] - lhist[t];
    __syncthreads();
    if (t < BROWS) lcur[t] = excl;
    const int grow = b * BROWS + t;
    if (t < BROWS && grow < NNODES) rp[grow] = base + excl;
    if (b == 0 && t == 0) rp[NNODES] = E;
    __syncthreads();

    // phase C: place sorted into LDS (strip lrow, keep 18-bit col)
    for (int i = t; i < cnt; i += 256) {
        const unsigned long long u = staged[base + i];
        const unsigned lo = (unsigned)(u & 0xffffffffu);
        const int lr  = (lo >> 18) & 127;
        const int pos = atomicAdd(&lcur[lr], 1);
        sbuf[pos] = (u & 0xffffffff00000000ull) | (lo & 0x3ffffu);
    }
    __syncthreads();

    // phase D: sequential coalesced global write
    for (int i = t; i < cnt; i += 256) cvs[base + i] = sbuf[i];
}

// ---------------- fused CSR SpMM layers ----------------
// One 16-lane quarter-wave per row; lane owns 4 consecutive dims (float4).
// MODE 1: xout = s,  out = emb + coef*s
// MODE 2: xout = s,  out += coef*s
// MODE 3:            out += coef*s
template <int MODE>
__global__ __launch_bounds__(256) void csr_layer(
    const int* __restrict__ rp, const unsigned long long* __restrict__ cvs,
    const float* __restrict__ xin, float* __restrict__ xout,
    const float* __restrict__ emb, float* __restrict__ out,
    float coef, int nqw)
{
    const int gtid = blockIdx.x * blockDim.x + threadIdx.x;
    const int qw   = gtid >> 4;
    const int l4   = (gtid & 15) * 4;

    for (int r = qw; r < NNODES; r += nqw) {
        const int e0 = rp[r], e1 = rp[r + 1];
        float4 acc = make_float4(0.f, 0.f, 0.f, 0.f);

        int e = e0;
        for (; e + 3 < e1; e += 4) {          // 4 independent 256B gathers
            const unsigned long long u0 = cvs[e],     u1 = cvs[e + 1];
            const unsigned long long u2 = cvs[e + 2], u3 = cvs[e + 3];
            const float4 a0 = *reinterpret_cast<const float4*>(xin + (unsigned)(u0 & 0xffffffffu) * EDIM + l4);
            const float4 a1 = *reinterpret_cast<const float4*>(xin + (unsigned)(u1 & 0xffffffffu) * EDIM + l4);
            const float4 a2 = *reinterpret_cast<const float4*>(xin + (unsigned)(u2 & 0xffffffffu) * EDIM + l4);
            const float4 a3 = *reinterpret_cast<const float4*>(xin + (unsigned)(u3 & 0xffffffffu) * EDIM + l4);
            const float v0 = __uint_as_float((unsigned)(u0 >> 32));
            const float v1 = __uint_as_float((unsigned)(u1 >> 32));
            const float v2 = __uint_as_float((unsigned)(u2 >> 32));
            const float v3 = __uint_as_float((unsigned)(u3 >> 32));
            acc.x += v0 * a0.x + v1 * a1.x + v2 * a2.x + v3 * a3.x;
            acc.y += v0 * a0.y + v1 * a1.y + v2 * a2.y + v3 * a3.y;
            acc.z += v0 * a0.z + v1 * a1.z + v2 * a2.z + v3 * a3.z;
            acc.w += v0 * a0.w + v1 * a1.w + v2 * a2.w + v3 * a3.w;
        }
        for (; e < e1; ++e) {
            const unsigned long long u0 = cvs[e];
            const float4 a0 = *reinterpret_cast<const float4*>(xin + (unsigned)(u0 & 0xffffffffu) * EDIM + l4);
            const float v0 = __uint_as_float((unsigned)(u0 >> 32));
            acc.x += v0 * a0.x; acc.y += v0 * a0.y;
            acc.z += v0 * a0.z; acc.w += v0 * a0.w;
        }

        if (MODE < 3)
            *reinterpret_cast<float4*>(xout + r * EDIM + l4) = acc;

        float4 base;
        if (MODE == 1)
            base = *reinterpret_cast<const float4*>(emb + r * EDIM + l4);
        else
            base = *reinterpret_cast<const float4*>(out + r * EDIM + l4);
        float4 o;
        o.x = base.x + coef * acc.x;
        o.y = base.y + coef * acc.y;
        o.z = base.z + coef * acc.z;
        o.w = base.w + coef * acc.w;
        *reinterpret_cast<float4*>(out + r * EDIM + l4) = o;
    }
}

// ---------------- fallback: COO atomic path (small ws) ----------------

__global__ __launch_bounds__(256) void spmm_kernel(
    const int* __restrict__ rows, const int* __restrict__ cols,
    const float* __restrict__ vals, const float* __restrict__ x,
    float* __restrict__ y, int E, int nqw)
{
    const int gtid = blockIdx.x * blockDim.x + threadIdx.x;
    const int qw   = gtid >> 4;
    const int l4   = (gtid & 15) * 4;
    for (int e = qw; e < E; e += nqw) {
        const int   c = cols[e];
        const int   r = rows[e];
        const float v = vals[e];
        const float4 xv = *reinterpret_cast<const float4*>(x + c * EDIM + l4);
        float* yp = y + r * EDIM + l4;
        atomicAdd(yp + 0, xv.x * v);
        atomicAdd(yp + 1, xv.y * v);
        atomicAdd(yp + 2, xv.z * v);
        atomicAdd(yp + 3, xv.w * v);
    }
}

__global__ __launch_bounds__(256) void combine_kernel(
    const float4* __restrict__ emb, const float4* __restrict__ x,
    float c, float4* __restrict__ out, int n4)
{
    int i = blockIdx.x * blockDim.x + threadIdx.x;
    const int stride = gridDim.x * blockDim.x;
    for (; i < n4; i += stride) {
        const float4 e = emb[i], a = x[i];
        out[i] = make_float4(e.x + c * a.x, e.y + c * a.y,
                             e.z + c * a.z, e.w + c * a.w);
    }
}

__global__ __launch_bounds__(256) void accum_kernel(
    float4* __restrict__ out, const float4* __restrict__ x, float c, int n4)
{
    int i = blockIdx.x * blockDim.x + threadIdx.x;
    const int stride = gridDim.x * blockDim.x;
    for (; i < n4; i += stride) {
        const float4 o0 = out[i], a = x[i];
        out[i] = make_float4(o0.x + c * a.x, o0.y + c * a.y,
                             o0.z + c * a.z, o0.w + c * a.w);
    }
}

// ---------------- launch ----------------

extern "C" void kernel_launch(void* const* d_in, const int* in_sizes, int n_in,
                              void* d_out, int out_size, void* d_ws, size_t ws_size,
                              hipStream_t stream)
{
    const int*   rows = (const int*)  d_in[0];
    const int*   cols = (const int*)  d_in[1];
    const float* vals = (const float*)d_in[2];
    const float* emb  = (const float*)d_in[3];
    float*       out  = (float*)d_out;

    const int E  = in_sizes[0];
    const int n  = NNODES * EDIM;                  // 9,600,000 floats
    const int n4 = n / 4;
    const size_t bufBytes = (size_t)n * sizeof(float);

    // per-block partition range, multiple of 4 for int4 loads
    const int per = ((((E + NB - 1) / NB) + 3) / 4) * 4;

    // ws layout (4-byte units; 8B-aligned offsets are even)
    const size_t o_gcnt   = 0;                          // NB*NBUCK = 150016
    const size_t o_btot   = (size_t)NB * NBUCK;
    const size_t o_bbase  = o_btot + 1184;
    const size_t o_rp     = o_bbase + 1184;
    const size_t o_cvs    = o_rp + 150016;              // even
    const size_t o_x1     = o_cvs + 2 * (size_t)E;
    const size_t o_staged = o_x1 + (size_t)n;           // x2 aliases staged
    const size_t needCSR  = (o_staged + 2 * (size_t)E) * 4;

    const int NQW     = 32768;                     // quarter-wave workers
    const int sblocks = NQW / 16;                  // 2048 blocks of 256

    if (ws_size >= needCSR) {
        int* gcnt  = (int*)d_ws + o_gcnt;
        int* btot  = (int*)d_ws + o_btot;
        int* bbase = (int*)d_ws + o_bbase;
        int* rp    = (int*)d_ws + o_rp;
        unsigned long long* cvs    = (unsigned long long*)((int*)d_ws + o_cvs);
        float*              x1     = (float*)d_ws + o_x1;
        unsigned long long* staged = (unsigned long long*)((int*)d_ws + o_staged);
        float*              x2     = (float*)staged;   // alias: staged dead after bsort

        pcount_kernel<<<NB, 256, 0, stream>>>(rows, gcnt, E, per);
        pscan1_kernel<<<(NBUCK + 255) / 256, 256, 0, stream>>>(gcnt, btot);
        bscan_kernel<<<1, 1024, 0, stream>>>(btot, bbase, E);
        pplace_kernel<<<NB, 256, 0, stream>>>(rows, cols, vals, gcnt, bbase, staged, E, per);
        bsort_kernel<<<NBUCK, 256, 0, stream>>>(bbase, staged, cvs, rp, E);

        csr_layer<1><<<sblocks, 256, 0, stream>>>(rp, cvs, emb, x1, emb, out, 0.5f, NQW);
        csr_layer<2><<<sblocks, 256, 0, stream>>>(rp, cvs, x1, x2, nullptr, out, 1.0f / 3.0f, NQW);
        csr_layer<3><<<sblocks, 256, 0, stream>>>(rp, cvs, x2, nullptr, nullptr, out, 0.25f, NQW);
    } else {
        // fallback: COO atomic path, 2 buffers
        float* wsA = (float*)d_ws;
        float* wsB = wsA + n;
        hipMemsetAsync(d_ws, 0, 2 * bufBytes, stream);
        spmm_kernel<<<sblocks, 256, 0, stream>>>(rows, cols, vals, emb, wsA, E, NQW);
        combine_kernel<<<2048, 256, 0, stream>>>(
            (const float4*)emb, (const float4*)wsA, 0.5f, (float4*)out, n4);
        spmm_kernel<<<sblocks, 256, 0, stream>>>(rows, cols, vals, wsA, wsB, E, NQW);
        accum_kernel<<<2048, 256, 0, stream>>>(
            (float4*)out, (const float4*)wsB, 1.0f / 3.0f, n4);
        hipMemsetAsync(wsA, 0, bufBytes, stream);
        spmm_kernel<<<sblocks, 256, 0, stream>>>(rows, cols, vals, wsB, wsA, E, NQW);
        accum_kernel<<<2048, 256, 0, stream>>>(
            (float4*)out, (const float4*)wsA, 0.25f, n4);
    }
}

// Round 9
// 609.542 us; speedup vs baseline: 20.1636x; 1.3538x over previous
//
#include <hip/hip_runtime.h>

// LightGCN propagation on MI355X.
// out = emb + A@emb/2 + A^2@emb/3 + A^3@emb/4, A given as COO (rows, cols, vals).
// N = 150000 nodes, D = 64, E = 4.8M edges.
//
// Build pipeline (round-7, proven): radix-partition with block-private runs
//   pcount/pscan1/bscan/pplace/bsort -> row-sorted cvs[] + rp[]
// Layers (round-8 change): hidden features stored BF16 (halves the dominant
// random-gather traffic: 256B -> 128B per row); accumulation + out stay F32.

#define NNODES 150000
#define EDIM   64
#define BROWS  128
#define NBUCK  ((NNODES + BROWS - 1) / BROWS)   // 1172
#define BCAP   6144                              // mean 4096, ~32 sigma headroom
#define NB     128                               // partition blocks

typedef unsigned short u16;
typedef unsigned long long ull;

__device__ inline float b2f(u16 h) { return __uint_as_float(((unsigned)h) << 16); }
__device__ inline u16 f2b(float f) {                       // RNE f32->bf16
    const unsigned x = __float_as_uint(f);
    const unsigned r = ((x >> 16) & 1u) + 0x7fffu;
    return (u16)((x + r) >> 16);
}

// ---------------- partition build ----------------

__global__ __launch_bounds__(256) void pcount_kernel(
    const int* __restrict__ rows, int* __restrict__ gcnt, int E, int per)
{
    __shared__ int lh[NBUCK];
    for (int i = threadIdx.x; i < NBUCK; i += 256) lh[i] = 0;
    __syncthreads();

    const int start = blockIdx.x * per;
    int end = start + per; if (end > E) end = E;
    const int vend = start + (((end - start) >> 2) << 2);

    const int4* r4 = (const int4*)(rows + start);
    const int nv = (vend - start) >> 2;
    for (int j = threadIdx.x; j < nv; j += 256) {
        const int4 r = r4[j];
        atomicAdd(&lh[r.x >> 7], 1);
        atomicAdd(&lh[r.y >> 7], 1);
        atomicAdd(&lh[r.z >> 7], 1);
        atomicAdd(&lh[r.w >> 7], 1);
    }
    for (int j = vend + threadIdx.x; j < end; j += 256)
        atomicAdd(&lh[rows[j] >> 7], 1);
    __syncthreads();

    int* g = gcnt + blockIdx.x * NBUCK;
    for (int i = threadIdx.x; i < NBUCK; i += 256) g[i] = lh[i];
}

__global__ __launch_bounds__(256) void pscan1_kernel(
    int* __restrict__ gcnt, int* __restrict__ btot)
{
    const int k = blockIdx.x * blockDim.x + threadIdx.x;
    if (k >= NBUCK) return;
    int run = 0;
    for (int c = 0; c < NB; c += 32) {
        int v[32];
        #pragma unroll
        for (int j = 0; j < 32; ++j) v[j] = gcnt[(c + j) * NBUCK + k];
        #pragma unroll
        for (int j = 0; j < 32; ++j) {
            const int t = v[j];
            gcnt[(c + j) * NBUCK + k] = run;
            run += t;
        }
    }
    btot[k] = run;
}

__global__ __launch_bounds__(1024) void bscan_kernel(
    const int* __restrict__ btot, int* __restrict__ bbase, int E)
{
    __shared__ int sh[2048];
    const int t = threadIdx.x;
    const int v0 = (t < NBUCK) ? btot[t] : 0;
    const int v1 = (t + 1024 < NBUCK) ? btot[t + 1024] : 0;
    sh[t] = v0; sh[t + 1024] = v1;
    __syncthreads();
    for (int off = 1; off < 2048; off <<= 1) {
        const int a = (t >= off) ? sh[t - off] : 0;
        const int b = (t + 1024 >= off) ? sh[t + 1024 - off] : 0;
        __syncthreads();
        sh[t] += a; sh[t + 1024] += b;
        __syncthreads();
    }
    if (t < NBUCK)        bbase[t]        = sh[t] - v0;
    if (t + 1024 < NBUCK) bbase[t + 1024] = sh[t + 1024] - v1;
    if (t == 0) bbase[NBUCK] = E;
}

__global__ __launch_bounds__(256) void pplace_kernel(
    const int* __restrict__ rows, const int* __restrict__ cols,
    const float* __restrict__ vals, const int* __restrict__ gcnt,
    const int* __restrict__ bbase, ull* __restrict__ staged,
    int E, int per)
{
    __shared__ int lcur[NBUCK];
    const int* g = gcnt + blockIdx.x * NBUCK;
    for (int i = threadIdx.x; i < NBUCK; i += 256)
        lcur[i] = bbase[i] + g[i];
    __syncthreads();

    const int start = blockIdx.x * per;
    int end = start + per; if (end > E) end = E;
    const int vend = start + (((end - start) >> 2) << 2);

    #define PL1(RR, CC, VV) {                                              \
        const int b_  = (RR) >> 7;                                         \
        const int lr_ = (RR) & 127;                                        \
        const int p_  = atomicAdd(&lcur[b_], 1);                           \
        staged[p_] = ((ull)__float_as_uint(VV) << 32) |                    \
                     (unsigned)((CC) | (lr_ << 18)); }

    const int4*   r4 = (const int4*)(rows + start);
    const int4*   c4 = (const int4*)(cols + start);
    const float4* v4 = (const float4*)(vals + start);
    const int nv = (vend - start) >> 2;
    for (int j = threadIdx.x; j < nv; j += 256) {
        const int4   r = r4[j];
        const int4   c = c4[j];
        const float4 v = v4[j];
        PL1(r.x, c.x, v.x)
        PL1(r.y, c.y, v.y)
        PL1(r.z, c.z, v.z)
        PL1(r.w, c.w, v.w)
    }
    for (int j = vend + threadIdx.x; j < end; j += 256)
        PL1(rows[j], cols[j], vals[j])
    #undef PL1
}

__global__ __launch_bounds__(256) void bsort_kernel(
    const int* __restrict__ bbase, const ull* __restrict__ staged,
    ull* __restrict__ cvs, int* __restrict__ rp, int E)
{
    __shared__ ull sbuf[BCAP];   // 48 KB
    __shared__ int lhist[BROWS];
    __shared__ int lcur[BROWS];

    const int b    = blockIdx.x;
    const int base = bbase[b];
    int cnt = bbase[b + 1] - base;
    if (cnt > BCAP) cnt = BCAP;
    const int t = threadIdx.x;

    if (t < BROWS) lhist[t] = 0;
    __syncthreads();

    for (int i = t; i < cnt; i += 256) {
        const unsigned lo = (unsigned)(staged[base + i] & 0xffffffffu);
        atomicAdd(&lhist[(lo >> 18) & 127], 1);
    }
    __syncthreads();

    if (t < BROWS) lcur[t] = lhist[t];
    __syncthreads();
    for (int off = 1; off < BROWS; off <<= 1) {
        int a = 0;
        if (t < BROWS && t >= off) a = lcur[t - off];
        __syncthreads();
        if (t < BROWS) lcur[t] += a;
        __syncthreads();
    }
    int excl = 0;
    if (t < BROWS) excl = lcur[t] - lhist[t];
    __syncthreads();
    if (t < BROWS) lcur[t] = excl;
    const int grow = b * BROWS + t;
    if (t < BROWS && grow < NNODES) rp[grow] = base + excl;
    if (b == 0 && t == 0) rp[NNODES] = E;
    __syncthreads();

    for (int i = t; i < cnt; i += 256) {
        const ull u = staged[base + i];
        const unsigned lo = (unsigned)(u & 0xffffffffu);
        const int lr  = (lo >> 18) & 127;
        const int pos = atomicAdd(&lcur[lr], 1);
        sbuf[pos] = (u & 0xffffffff00000000ull) | (lo & 0x3ffffu);
    }
    __syncthreads();

    for (int i = t; i < cnt; i += 256) cvs[base + i] = sbuf[i];
}

// ---------------- emb f32 -> bf16 ----------------

__global__ __launch_bounds__(256) void econv_kernel(
    const float4* __restrict__ in, ushort4* __restrict__ outh, int n4)
{
    int i = blockIdx.x * blockDim.x + threadIdx.x;
    const int stride = gridDim.x * blockDim.x;
    for (; i < n4; i += stride) {
        const float4 f = in[i];
        ushort4 h;
        h.x = f2b(f.x); h.y = f2b(f.y); h.z = f2b(f.z); h.w = f2b(f.w);
        outh[i] = h;
    }
}

// ---------------- fused CSR SpMM layers (bf16 gather, f32 accumulate) -------
// One 16-lane quarter-wave per row; lane owns 4 consecutive dims.
// MODE 1: xout = bf16(s), out = emb + coef*s
// MODE 2: xout = bf16(s), out += coef*s
// MODE 3:                 out += coef*s
template <int MODE>
__global__ __launch_bounds__(256) void csr_layer(
    const int* __restrict__ rp, const ull* __restrict__ cvs,
    const u16* __restrict__ xin, u16* __restrict__ xout,
    const float* __restrict__ emb, float* __restrict__ out,
    float coef, int nqw)
{
    const int gtid = blockIdx.x * blockDim.x + threadIdx.x;
    const int qw   = gtid >> 4;
    const int l4   = (gtid & 15) * 4;

    for (int r = qw; r < NNODES; r += nqw) {
        const int e0 = rp[r], e1 = rp[r + 1];
        float4 acc = make_float4(0.f, 0.f, 0.f, 0.f);

        int e = e0;
        for (; e + 3 < e1; e += 4) {          // 4 independent 128B row gathers
            const ull u0 = cvs[e],     u1 = cvs[e + 1];
            const ull u2 = cvs[e + 2], u3 = cvs[e + 3];
            const ushort4 h0 = *reinterpret_cast<const ushort4*>(xin + (unsigned)(u0 & 0x3ffffu) * EDIM + l4);
            const ushort4 h1 = *reinterpret_cast<const ushort4*>(xin + (unsigned)(u1 & 0x3ffffu) * EDIM + l4);
            const ushort4 h2 = *reinterpret_cast<const ushort4*>(xin + (unsigned)(u2 & 0x3ffffu) * EDIM + l4);
            const ushort4 h3 = *reinterpret_cast<const ushort4*>(xin + (unsigned)(u3 & 0x3ffffu) * EDIM + l4);
            const float v0 = __uint_as_float((unsigned)(u0 >> 32));
            const float v1 = __uint_as_float((unsigned)(u1 >> 32));
            const float v2 = __uint_as_float((unsigned)(u2 >> 32));
            const float v3 = __uint_as_float((unsigned)(u3 >> 32));
            acc.x += v0 * b2f(h0.x) + v1 * b2f(h1.x) + v2 * b2f(h2.x) + v3 * b2f(h3.x);
            acc.y += v0 * b2f(h0.y) + v1 * b2f(h1.y) + v2 * b2f(h2.y) + v3 * b2f(h3.y);
            acc.z += v0 * b2f(h0.z) + v1 * b2f(h1.z) + v2 * b2f(h2.z) + v3 * b2f(h3.z);
            acc.w += v0 * b2f(h0.w) + v1 * b2f(h1.w) + v2 * b2f(h2.w) + v3 * b2f(h3.w);
        }
        for (; e < e1; ++e) {
            const ull u0 = cvs[e];
            const ushort4 h0 = *reinterpret_cast<const ushort4*>(xin + (unsigned)(u0 & 0x3ffffu) * EDIM + l4);
            const float v0 = __uint_as_float((unsigned)(u0 >> 32));
            acc.x += v0 * b2f(h0.x); acc.y += v0 * b2f(h0.y);
            acc.z += v0 * b2f(h0.z); acc.w += v0 * b2f(h0.w);
        }

        if (MODE < 3) {
            ushort4 h;
            h.x = f2b(acc.x); h.y = f2b(acc.y); h.z = f2b(acc.z); h.w = f2b(acc.w);
            *reinterpret_cast<ushort4*>(xout + r * EDIM + l4) = h;
        }

        float4 base;
        if (MODE == 1)
            base = *reinterpret_cast<const float4*>(emb + r * EDIM + l4);
        else
            base = *reinterpret_cast<const float4*>(out + r * EDIM + l4);
        float4 o;
        o.x = base.x + coef * acc.x;
        o.y = base.y + coef * acc.y;
        o.z = base.z + coef * acc.z;
        o.w = base.w + coef * acc.w;
        *reinterpret_cast<float4*>(out + r * EDIM + l4) = o;
    }
}

// ---------------- fallback: COO atomic path (small ws) ----------------

__global__ __launch_bounds__(256) void spmm_kernel(
    const int* __restrict__ rows, const int* __restrict__ cols,
    const float* __restrict__ vals, const float* __restrict__ x,
    float* __restrict__ y, int E, int nqw)
{
    const int gtid = blockIdx.x * blockDim.x + threadIdx.x;
    const int qw   = gtid >> 4;
    const int l4   = (gtid & 15) * 4;
    for (int e = qw; e < E; e += nqw) {
        const int   c = cols[e];
        const int   r = rows[e];
        const float v = vals[e];
        const float4 xv = *reinterpret_cast<const float4*>(x + c * EDIM + l4);
        float* yp = y + r * EDIM + l4;
        atomicAdd(yp + 0, xv.x * v);
        atomicAdd(yp + 1, xv.y * v);
        atomicAdd(yp + 2, xv.z * v);
        atomicAdd(yp + 3, xv.w * v);
    }
}

__global__ __launch_bounds__(256) void combine_kernel(
    const float4* __restrict__ emb, const float4* __restrict__ x,
    float c, float4* __restrict__ out, int n4)
{
    int i = blockIdx.x * blockDim.x + threadIdx.x;
    const int stride = gridDim.x * blockDim.x;
    for (; i < n4; i += stride) {
        const float4 e = emb[i], a = x[i];
        out[i] = make_float4(e.x + c * a.x, e.y + c * a.y,
                             e.z + c * a.z, e.w + c * a.w);
    }
}

__global__ __launch_bounds__(256) void accum_kernel(
    float4* __restrict__ out, const float4* __restrict__ x, float c, int n4)
{
    int i = blockIdx.x * blockDim.x + threadIdx.x;
    const int stride = gridDim.x * blockDim.x;
    for (; i < n4; i += stride) {
        const float4 o0 = out[i], a = x[i];
        out[i] = make_float4(o0.x + c * a.x, o0.y + c * a.y,
                             o0.z + c * a.z, o0.w + c * a.w);
    }
}

// ---------------- launch ----------------

extern "C" void kernel_launch(void* const* d_in, const int* in_sizes, int n_in,
                              void* d_out, int out_size, void* d_ws, size_t ws_size,
                              hipStream_t stream)
{
    const int*   rows = (const int*)  d_in[0];
    const int*   cols = (const int*)  d_in[1];
    const float* vals = (const float*)d_in[2];
    const float* emb  = (const float*)d_in[3];
    float*       out  = (float*)d_out;

    const int E  = in_sizes[0];
    const int n  = NNODES * EDIM;                  // 9,600,000 floats
    const int n4 = n / 4;
    const size_t bufBytes = (size_t)n * sizeof(float);

    const int per = ((((E + NB - 1) / NB) + 3) / 4) * 4;

    // ws layout (4-byte units; 8B-aligned offsets are even)
    const size_t o_gcnt   = 0;                          // NB*NBUCK = 150016
    const size_t o_btot   = (size_t)NB * NBUCK;
    const size_t o_bbase  = o_btot + 1184;
    const size_t o_rp     = o_bbase + 1184;
    const size_t o_cvs    = o_rp + 150016;              // even
    const size_t o_embh   = o_cvs + 2 * (size_t)E;      // n/2 units (bf16)
    const size_t o_x1h    = o_embh + (size_t)n / 2;
    const size_t o_staged = o_x1h + (size_t)n / 2;      // x2h aliases staged
    const size_t needCSR  = (o_staged + 2 * (size_t)E) * 4;

    const int NQW     = 32768;
    const int sblocks = NQW / 16;

    if (ws_size >= needCSR) {
        int* gcnt  = (int*)d_ws + o_gcnt;
        int* btot  = (int*)d_ws + o_btot;
        int* bbase = (int*)d_ws + o_bbase;
        int* rp    = (int*)d_ws + o_rp;
        ull*  cvs    = (ull*)((int*)d_ws + o_cvs);
        u16*  embh   = (u16*)((int*)d_ws + o_embh);
        u16*  x1h    = (u16*)((int*)d_ws + o_x1h);
        ull*  staged = (ull*)((int*)d_ws + o_staged);
        u16*  x2h    = (u16*)staged;                   // alias: staged dead after bsort

        pcount_kernel<<<NB, 256, 0, stream>>>(rows, gcnt, E, per);
        pscan1_kernel<<<(NBUCK + 255) / 256, 256, 0, stream>>>(gcnt, btot);
        bscan_kernel<<<1, 1024, 0, stream>>>(btot, bbase, E);
        pplace_kernel<<<NB, 256, 0, stream>>>(rows, cols, vals, gcnt, bbase, staged, E, per);
        bsort_kernel<<<NBUCK, 256, 0, stream>>>(bbase, staged, cvs, rp, E);
        econv_kernel<<<1024, 256, 0, stream>>>((const float4*)emb, (ushort4*)embh, n4);

        csr_layer<1><<<sblocks, 256, 0, stream>>>(rp, cvs, embh, x1h, emb, out, 0.5f, NQW);
        csr_layer<2><<<sblocks, 256, 0, stream>>>(rp, cvs, x1h, x2h, nullptr, out, 1.0f / 3.0f, NQW);
        csr_layer<3><<<sblocks, 256, 0, stream>>>(rp, cvs, x2h, nullptr, nullptr, out, 0.25f, NQW);
    } else {
        // fallback: COO atomic path, 2 buffers (f32)
        float* wsA = (float*)d_ws;
        float* wsB = wsA + n;
        hipMemsetAsync(d_ws, 0, 2 * bufBytes, stream);
        spmm_kernel<<<sblocks, 256, 0, stream>>>(rows, cols, vals, emb, wsA, E, NQW);
        combine_kernel<<<2048, 256, 0, stream>>>(
            (const float4*)emb, (const float4*)wsA, 0.5f, (float4*)out, n4);
        spmm_kernel<<<sblocks, 256, 0, stream>>>(rows, cols, vals, wsA, wsB, E, NQW);
        accum_kernel<<<2048, 256, 0, stream>>>(
            (float4*)out, (const float4*)wsB, 1.0f / 3.0f, n4);
        hipMemsetAsync(wsA, 0, bufBytes, stream);
        spmm_kernel<<<sblocks, 256, 0, stream>>>(rows, cols, vals, wsB, wsA, E, NQW);
        accum_kernel<<<2048, 256, 0, stream>>>(
            (float4*)out, (const float4*)wsA, 0.25f, n4);
    }
}